// Round 14
// baseline (1601.640 us; speedup 1.0000x reference)
//
#include <hip/hip_runtime.h>
#include <hip/hip_bf16.h>
#include <math.h>

// ---------- constants ----------
#define BB 4
#define TT 1024
#define BT 4096          // B*T
#define EE 1024
#define HH 16
#define HSZ 64
#define LL 4
#define HID 4096
#define VV 32000
#define LOG2E 1.44269504f

typedef __attribute__((ext_vector_type(8))) __bf16 bf16x8;
typedef __attribute__((ext_vector_type(4))) __bf16 bf16x4;
typedef __attribute__((ext_vector_type(4))) float f32x4;

#define MFMA16(a, b, c) __builtin_amdgcn_mfma_f32_16x16x32_bf16((a), (b), (c), 0, 0, 0)

// swizzled offset in a 32-element (bf16) LDS row: 4 chunks of 8 elems,
// chunk ^= (row>>1)&3 -> 16B ds_read_b128 stays ~2-way conflict (free).
__device__ __forceinline__ int swz32(int row, int chunk) {
    return row * 32 + ((chunk ^ ((row >> 1) & 3)) << 3);
}

// async global->LDS, 16B per lane; LDS dest is WAVE-UNIFORM base + lane*16.
__device__ __forceinline__ void gload16(const __bf16* g, __bf16* l) {
    __builtin_amdgcn_global_load_lds(
        (const __attribute__((address_space(1))) unsigned int*)g,
        (__attribute__((address_space(3))) unsigned int*)l, 16, 0, 0);
}

// ---------- transpose + f32->bf16 convert:  in [R][C] f32  ->  out [C][R] bf16 ----------
__global__ __launch_bounds__(256) void transpose_conv(
    const float* __restrict__ in, __bf16* __restrict__ out,
    int R, int C, long ibs, int bdiv, long os1, long os2)
{
    __shared__ __bf16 tile[64][65];
    const int t = threadIdx.x;
    const int c0 = blockIdx.x * 64, r0 = blockIdx.y * 64;
    const int batch = blockIdx.z;
    const float* ib = in + (size_t)batch * ibs;
    __bf16* ob = out + (size_t)(batch / bdiv) * os1 + (size_t)(batch % bdiv) * os2;
#pragma unroll
    for (int p = 0; p < 4; ++p) {
        const int r = (t >> 4) + p * 16;
        const int c = (t & 15) * 4;
        float4 v = *(const float4*)(ib + (size_t)(r0 + r) * C + c0 + c);
        tile[c + 0][r] = (__bf16)v.x;
        tile[c + 1][r] = (__bf16)v.y;
        tile[c + 2][r] = (__bf16)v.z;
        tile[c + 3][r] = (__bf16)v.w;
    }
    __syncthreads();
#pragma unroll
    for (int p = 0; p < 2; ++p) {
        const int g = t + p * 256;
        const int co = g >> 3, ch = g & 7;
        bf16x8 vv;
#pragma unroll
        for (int j = 0; j < 8; ++j) vv[j] = tile[co][ch * 8 + j];
        *(bf16x8*)(ob + (size_t)(c0 + co) * R + r0 + ch * 8) = vv;
    }
}

// merged QKV-weight transpose: z in [0,192) -> which = z/64 (q/k/v), sub = z%64.
__global__ __launch_bounds__(256) void transpose_qkv(
    const float* __restrict__ wq, const float* __restrict__ wk,
    const float* __restrict__ wv, __bf16* __restrict__ out)
{
    __shared__ __bf16 tile[64][65];
    const int t = threadIdx.x;
    const int r0 = blockIdx.y * 64;
    const int which = blockIdx.z >> 6, sub = blockIdx.z & 63;
    const float* src = (which == 0) ? wq : (which == 1) ? wk : wv;
    const float* ib = src + (size_t)sub * 65536;
    __bf16* ob = out + (size_t)(sub >> 4) * 3145728 + (size_t)which * 1048576
               + (size_t)(sub & 15) * 65536;
#pragma unroll
    for (int p = 0; p < 4; ++p) {
        const int r = (t >> 4) + p * 16;
        const int c = (t & 15) * 4;
        float4 v = *(const float4*)(ib + (size_t)(r0 + r) * 64 + c);
        tile[c + 0][r] = (__bf16)v.x;
        tile[c + 1][r] = (__bf16)v.y;
        tile[c + 2][r] = (__bf16)v.z;
        tile[c + 3][r] = (__bf16)v.w;
    }
    __syncthreads();
#pragma unroll
    for (int p = 0; p < 2; ++p) {
        const int g = t + p * 256;
        const int co = g >> 3, ch = g & 7;
        bf16x8 vv;
#pragma unroll
        for (int j = 0; j < 8; ++j) vv[j] = tile[co][ch * 8 + j];
        *(bf16x8*)(ob + (size_t)co * 1024 + r0 + ch * 8) = vv;
    }
}

// ---------- embedding + sinusoidal positional encoding (bf16 residual) ----------
__global__ __launch_bounds__(256) void embed_kernel(
    const int* __restrict__ idx, const float* __restrict__ emb, __bf16* __restrict__ x)
{
    const int row = blockIdx.x, tid = threadIdx.x;
    const float pos = (float)(row & (TT - 1));
    const int tok = idx[row];
    const int cb = tid * 4;
    float4 ev = *(const float4*)(emb + (size_t)tok * EE + cb);
    const float kk = -9.2103403720f / (float)EE;   // -ln(10000)/E
    float pe[4];
#pragma unroll
    for (int j = 0; j < 4; ++j) {
        const int c = cb + j;
        const float div = expf(kk * (float)(c & ~1));
        const float ang = pos * div;
        pe[j] = (c & 1) ? cosf(ang) : sinf(ang);
    }
    bf16x4 r;
    r[0] = (__bf16)(ev.x * 32.0f + pe[0]);
    r[1] = (__bf16)(ev.y * 32.0f + pe[1]);
    r[2] = (__bf16)(ev.z * 32.0f + pe[2]);
    r[3] = (__bf16)(ev.w * 32.0f + pe[3]);
    *(bf16x4*)(x + (size_t)row * EE + cb) = r;
}

// ---------- LayerNorm (bf16 in -> bf16 out), one block per row of 1024 ----------
__global__ __launch_bounds__(256) void ln_kernel(
    const __bf16* __restrict__ x, const float* __restrict__ g,
    const float* __restrict__ be, __bf16* __restrict__ out)
{
    __shared__ float red[2][4];
    const int row = blockIdx.x, tid = threadIdx.x;
    bf16x4 xv = *(const bf16x4*)(x + (size_t)row * EE + tid * 4);
    float v0 = (float)xv[0], v1 = (float)xv[1], v2 = (float)xv[2], v3 = (float)xv[3];
    float s = v0 + v1 + v2 + v3;
    float ss = v0 * v0 + v1 * v1 + v2 * v2 + v3 * v3;
#pragma unroll
    for (int m = 1; m < 64; m <<= 1) { s += __shfl_xor(s, m); ss += __shfl_xor(ss, m); }
    if ((tid & 63) == 0) { red[0][tid >> 6] = s; red[1][tid >> 6] = ss; }
    __syncthreads();
    s  = red[0][0] + red[0][1] + red[0][2] + red[0][3];
    ss = red[1][0] + red[1][1] + red[1][2] + red[1][3];
    const float mean = s * (1.0f / EE);
    const float var  = ss * (1.0f / EE) - mean * mean;
    const float rs   = rsqrtf(var + 1e-5f);
    float4 gv = *(const float4*)(g + tid * 4);
    float4 bv = *(const float4*)(be + tid * 4);
    __bf16* o = out + (size_t)row * EE + tid * 4;
    o[0] = (__bf16)((v0 - mean) * rs * gv.x + bv.x);
    o[1] = (__bf16)((v1 - mean) * rs * gv.y + bv.y);
    o[2] = (__bf16)((v2 - mean) * rs * gv.z + bv.z);
    o[3] = (__bf16)((v3 - mean) * rs * gv.w + bv.w);
}

// ---------- GEMM: C[M,N] = A[M,K](bf16) * Bt[N,K](bf16)^T  (+epilogue) ----------
// MODE 0: out bf16            MODE 1: out bf16, +bias, relu
// MODE 2: Cb(bf16) += acc + bias (residual stream)
// MODE 4: Cf32 = acc + bias, plus per-row fixed-max sumexp partial -> part[row][bn]
// MODE 5: QKV: Q,K blocks (n0<2048) -> bf16 Cb; V blocks (n0>=2048) -> LDS-bounce
//         transpose -> coalesced vT[b][h][e][t] stores.
// GSWZ: 1D grid, XCD-stripe mapping (requires M==4096 -> 32 m-blocks).
template <int MODE, int GSWZ, int BN>
__global__ __launch_bounds__(256, 2) void gemm_bt(
    const __bf16* __restrict__ A, const __bf16* __restrict__ Bt,
    const float* __restrict__ bias, float* __restrict__ C,
    __bf16* __restrict__ Cb, __bf16* __restrict__ Vx,
    float* __restrict__ part, int M, int N, int K)
{
    constexpr int JW  = BN / 32;   // j-fragments per wave
    constexpr int BSW = BN / 64;   // B staging gloads per wave
    __shared__ __bf16 As[128 * 32];
    __shared__ __bf16 Bs[BN * 32];
    __shared__ float redS[(MODE == 4) ? 128 : 1][2];
    __shared__ __bf16 Vb[(MODE == 5) ? 64 * 136 : 1];   // transpose bounce, pad 8

    const int tid = threadIdx.x;
    const int lane = tid & 63, wid = tid >> 6;
    const int wr = wid >> 1, wc = wid & 1;
    int bm, bn;
    if (GSWZ) {
        const int b = blockIdx.x;      // 8 XCDs x (4 m-stripes x N-sweep)
        const int j = b >> 3;
        bm = (b & 7) * 4 + (j & 3);
        bn = j >> 2;
    } else {
        bm = blockIdx.y; bn = blockIdx.x;
    }
    const int m0 = bm * 128, n0 = bn * BN;

    // staging: linear LDS dest, inverse-swizzled global source.
    size_t sA[2];  int loA[2];
#pragma unroll
    for (int c = 0; c < 2; ++c) {
        const int seg = wid * 2 + c;
        const int rl = seg * 16 + (lane >> 2);
        const int cl = (lane & 3) ^ ((rl >> 1) & 3);
        loA[c] = seg * 512;
        sA[c] = (size_t)(m0 + rl) * K + cl * 8;
    }
    size_t sB[BSW]; int loB[BSW];
#pragma unroll
    for (int c = 0; c < BSW; ++c) {
        const int seg = wid * BSW + c;
        const int rl = seg * 16 + (lane >> 2);
        const int cl = (lane & 3) ^ ((rl >> 1) & 3);
        loB[c] = seg * 512;
        sB[c] = (size_t)(n0 + rl) * K + cl * 8;
    }

    const int l15 = lane & 15, kch = lane >> 4;
    const int abase = swz32(wr * 64 + l15, kch);
    const int bbase = swz32(wc * (BN / 2) + l15, kch);

    f32x4 acc[4][JW] = {};

    const int nk = K >> 5;
    for (int kt = 0; kt < nk; ++kt) {
        const size_t ko = (size_t)kt * 32;
#pragma unroll
        for (int c = 0; c < 2; ++c)   gload16(A + sA[c] + ko, As + loA[c]);
#pragma unroll
        for (int c = 0; c < BSW; ++c) gload16(Bt + sB[c] + ko, Bs + loB[c]);
        __syncthreads();
        bf16x8 af[4], bfr[JW];
#pragma unroll
        for (int i = 0; i < 4; ++i)  af[i]  = *(const bf16x8*)(As + abase + i * 512);
#pragma unroll
        for (int j = 0; j < JW; ++j) bfr[j] = *(const bf16x8*)(Bs + bbase + j * 512);
#pragma unroll
        for (int i = 0; i < 4; ++i)
#pragma unroll
            for (int j = 0; j < JW; ++j)
                acc[i][j] = MFMA16(af[i], bfr[j], acc[i][j]);
        __syncthreads();
    }

    const int crow = m0 + wr * 64 + ((lane >> 4) << 2);
    const int ccol = n0 + wc * (BN / 2) + l15;

    if (MODE == 5 && n0 >= 2048) {
        // ---- V block: LDS-bounce transpose -> coalesced vT[b][h][e][t] ----
        const int bb = m0 >> 10, tl0 = m0 & 1023;
#pragma unroll
        for (int hf = 0; hf < 2; ++hf) {
            if (wc == hf) {
#pragma unroll
                for (int i = 0; i < 4; ++i)
#pragma unroll
                    for (int j = 0; j < JW; ++j) {
                        const int cl = l15 + j * 16;           // 0..63 in half
                        const int rl = wr * 64 + ((lane >> 4) << 2) + i * 16;
#pragma unroll
                        for (int r = 0; r < 4; ++r)
                            Vb[cl * 136 + rl + r] = (__bf16)acc[i][j][r];
                    }
            }
            __syncthreads();
            {
                const int hh2 = (n0 + hf * 64 - 2048) >> 6;
                const int e_loc = tid >> 2, t0 = (tid & 3) * 32;
                __bf16* gp = Vx + ((((size_t)bb * HH + hh2) * HSZ + e_loc) << 10)
                           + tl0 + t0;
#pragma unroll
                for (int k = 0; k < 4; ++k)
                    *(bf16x8*)(gp + k * 8) = *(const bf16x8*)(&Vb[e_loc * 136 + t0 + k * 8]);
            }
            __syncthreads();
        }
    } else {
#pragma unroll
        for (int i = 0; i < 4; ++i)
#pragma unroll
            for (int j = 0; j < JW; ++j) {
                const int cc = ccol + j * 16;
#pragma unroll
                for (int r = 0; r < 4; ++r) {
                    const size_t oidx = (size_t)(crow + i * 16 + r) * N + cc;
                    float v = acc[i][j][r];
                    if (MODE == 0 || MODE == 5) {
                        Cb[oidx] = (__bf16)v;
                    } else if (MODE == 1) {
                        v += bias[cc];
                        Cb[oidx] = (__bf16)(v > 0.0f ? v : 0.0f);
                    } else if (MODE == 2) {
                        Cb[oidx] = (__bf16)((float)Cb[oidx] + v + bias[cc]);
                    } else {
                        C[oidx] = v + bias[cc];
                    }
                }
            }
    }

    if constexpr (MODE == 4) {
        // per-row sumexp (fixed max = 0) over this block's 128 columns
        const int lg = lane >> 4;
#pragma unroll
        for (int i = 0; i < 4; ++i)
#pragma unroll
            for (int r = 0; r < 4; ++r) {
                float sm = 0.0f;
#pragma unroll
                for (int j = 0; j < 4; ++j)
                    sm += exp2f((acc[i][j][r] + bias[ccol + j * 16]) * LOG2E);
                sm += __shfl_xor(sm, 1);
                sm += __shfl_xor(sm, 2);
                sm += __shfl_xor(sm, 4);
                sm += __shfl_xor(sm, 8);
                if (l15 == 0)
                    redS[wr * 64 + i * 16 + lg * 4 + r][wc] = sm;
            }
        __syncthreads();
        if (tid < 128)
            part[(size_t)(m0 + tid) * (N >> 7) + bn] = redS[tid][0] + redS[tid][1];
    }
}

// ---------- causal flash attention: Q,K from qkv [BT][3072], V^T from vT ----------
// grid (B*H, T/16), ONE wave per block, 16 q-rows/wave, 32-key tiles.
// Shuffle-free softmax (rare __any rescale trigger), exact MFMA row-sum (lsum),
// PV B-fragments loaded directly from L2-resident vT (issued before softmax).
__global__ __launch_bounds__(64) void attn_kernel(
    const __bf16* __restrict__ qkv, const __bf16* __restrict__ vT,
    __bf16* __restrict__ out)
{
    __shared__ __bf16 Pl[16 * 32];
    const int lane = threadIdx.x;
    const int bh = blockIdx.x, b = bh >> 4, hh = bh & 15;
    const int qbase = (63 - blockIdx.y) * 16;   // LPT: longest blocks first
    const int RS = 3 * EE;  // row stride of qkv
    const __bf16* qp = qkv + (size_t)(b * TT) * RS + hh * HSZ;
    const __bf16* kp = qp + EE;
    const __bf16* vp = vT + ((size_t)(b * HH + hh) << 16);   // [64 e][1024 t]
    const int l15 = lane & 15, lg = lane >> 4;

    bf16x8 aq[2];
#pragma unroll
    for (int e = 0; e < 2; ++e)
        aq[e] = *(const bf16x8*)(qp + (size_t)(qbase + l15) * RS + e * 32 + lg * 8);

    bf16x8 ones;
#pragma unroll
    for (int j = 0; j < 8; ++j) ones[j] = (__bf16)1.0f;

    f32x4 ao[4] = {};
    f32x4 lsum = {};           // exact row-sums of P, via MFMA(P, ones)
    float mrun[4];
#pragma unroll
    for (int r = 0; r < 4; ++r) mrun[r] = -1e30f;

    const int ntile = qbase / 32 + 1;
    for (int st = 0; st < ntile; ++st) {
        const int sbase = st * 32;
        f32x4 as[2] = {};
        __builtin_amdgcn_s_setprio(1);
#pragma unroll
        for (int n = 0; n < 2; ++n)
#pragma unroll
            for (int e = 0; e < 2; ++e) {
                bf16x8 bk = *(const bf16x8*)(kp + (size_t)(sbase + n * 16 + l15) * RS + e * 32 + lg * 8);
                as[n] = MFMA16(aq[e], bk, as[n]);
            }
        __builtin_amdgcn_s_setprio(0);
        // issue V B-fragment loads early (L2-resident panel): latency hides
        // under the softmax VALU below.
        bf16x8 bvr[4];
#pragma unroll
        for (int n = 0; n < 4; ++n)
            bvr[n] = *(const bf16x8*)(vp + ((n * 16 + l15) << 10) + sbase + lg * 8);
        // scale + mask into registers; per-lane defer-max trigger check
        bool trig = false;
#pragma unroll
        for (int r = 0; r < 4; ++r) {
            const int qi = qbase + lg * 4 + r;
            float s0 = as[0][r] * 0.125f;
            float s1 = as[1][r] * 0.125f;
            if (sbase + l15 > qi)      s0 = -1e30f;
            if (sbase + 16 + l15 > qi) s1 = -1e30f;
            as[0][r] = s0; as[1][r] = s1;
            trig = trig || (s0 > mrun[r] + 8.0f) || (s1 > mrun[r] + 8.0f);
        }
        if (__any(trig)) {   // rare (typically tile 0 only): full rescale
#pragma unroll
            for (int r = 0; r < 4; ++r) {
                float rm = fmaxf(as[0][r], as[1][r]);
                rm = fmaxf(rm, __shfl_xor(rm, 1));
                rm = fmaxf(rm, __shfl_xor(rm, 2));
                rm = fmaxf(rm, __shfl_xor(rm, 4));
                rm = fmaxf(rm, __shfl_xor(rm, 8));
                const float mnew = fmaxf(mrun[r], rm);
                const float alpha = exp2f((mrun[r] - mnew) * LOG2E);
                lsum[r] *= alpha;
#pragma unroll
                for (int n = 0; n < 4; ++n) ao[n][r] *= alpha;
                mrun[r] = mnew;
            }
        }
#pragma unroll
        for (int r = 0; r < 4; ++r) {
            const float p0 = exp2f((as[0][r] - mrun[r]) * LOG2E);  // <= e^8
            const float p1 = exp2f((as[1][r] - mrun[r]) * LOG2E);
            const int prow = lg * 4 + r;
            Pl[swz32(prow, l15 >> 3) + (l15 & 7)] = (__bf16)p0;
            Pl[swz32(prow, (16 + l15) >> 3) + (l15 & 7)] = (__bf16)p1;
        }
        asm volatile("s_waitcnt lgkmcnt(0)" ::: "memory");
        bf16x8 pa = *(const bf16x8*)(&Pl[swz32(l15, lg)]);
        __builtin_amdgcn_s_setprio(1);
#pragma unroll
        for (int n = 0; n < 4; ++n)
            ao[n] = MFMA16(pa, bvr[n], ao[n]);
        lsum = MFMA16(pa, ones, lsum);   // exact row-sum accumulation
        __builtin_amdgcn_s_setprio(0);
    }
#pragma unroll
    for (int r = 0; r < 4; ++r) {
        const float inv = 1.0f / lsum[r];
        const int row = qbase + lg * 4 + r;
#pragma unroll
        for (int n = 0; n < 4; ++n)
            out[(size_t)(b * TT + row) * EE + hh * HSZ + n * 16 + l15] =
                (__bf16)(ao[n][r] * inv);
    }
}

// ---------- merge per-block sumexp partials + target gather ----------
__global__ __launch_bounds__(256) void loss_reduce(
    const float* __restrict__ part, const float* __restrict__ logits,
    const int* __restrict__ tgt, float* __restrict__ lossv, int NP)
{
    __shared__ float rs2[4];
    const int row = blockIdx.x, tid = threadIdx.x;
    float s = (tid < NP) ? part[(size_t)row * NP + tid] : 0.0f;
#pragma unroll
    for (int k = 1; k < 64; k <<= 1) s += __shfl_xor(s, k);
    if ((tid & 63) == 0) rs2[tid >> 6] = s;
    __syncthreads();
    if (tid == 0) {
        const float S = rs2[0] + rs2[1] + rs2[2] + rs2[3];
        lossv[row] = logf(S) - logits[(size_t)row * VV + tgt[row]];
    }
}

__global__ __launch_bounds__(256) void loss_final(const float* __restrict__ lossv, float* __restrict__ out)
{
    __shared__ float red[4];
    const int tid = threadIdx.x;
    float s = 0.0f;
    for (int i = tid; i < BT; i += 256) s += lossv[i];
#pragma unroll
    for (int k = 1; k < 64; k <<= 1) s += __shfl_xor(s, k);
    if ((tid & 63) == 0) red[tid >> 6] = s;
    __syncthreads();
    if (tid == 0) out[0] = (red[0] + red[1] + red[2] + red[3]) * (1.0f / BT);
}

// ---------- launcher ----------
extern "C" void kernel_launch(void* const* d_in, const int* in_sizes, int n_in,
                              void* d_out, int out_size, void* d_ws, size_t ws_size,
                              hipStream_t stream)
{
    const int*   idx   = (const int*)d_in[0];
    const int*   tgt   = (const int*)d_in[1];
    const float* temb  = (const float*)d_in[2];
    const float* ln1g  = (const float*)d_in[3];
    const float* ln1b  = (const float*)d_in[4];
    const float* wq    = (const float*)d_in[5];
    const float* wk    = (const float*)d_in[6];
    const float* wv    = (const float*)d_in[7];
    const float* wo    = (const float*)d_in[8];
    const float* bo    = (const float*)d_in[9];
    const float* ln2g  = (const float*)d_in[10];
    const float* ln2b  = (const float*)d_in[11];
    const float* w1    = (const float*)d_in[12];
    const float* b1    = (const float*)d_in[13];
    const float* w2    = (const float*)d_in[14];
    const float* b2    = (const float*)d_in[15];
    const float* lnfg  = (const float*)d_in[16];
    const float* lnfb  = (const float*)d_in[17];
    const float* lm_w  = (const float*)d_in[18];
    const float* lm_b  = (const float*)d_in[19];

    float* logits  = (float*)d_out;
    float* lossout = logits + (size_t)BT * VV;

    char* ws = (char*)d_ws;
    size_t off = 0;
    auto carve = [&](size_t bytes) {
        void* p = ws + off;
        off += (bytes + 255) & ~(size_t)255;
        return p;
    };
    __bf16* WQKVT = (__bf16*)carve((size_t)LL * 3072 * 1024 * 2);  // [L][3072][1024]
    __bf16* WOT   = (__bf16*)carve((size_t)LL * 1024 * 1024 * 2);  // [L][1024][1024]
    __bf16* W1T   = (__bf16*)carve((size_t)LL * 4096 * 1024 * 2);  // [L][4096][1024]
    __bf16* W2T   = (__bf16*)carve((size_t)LL * 1024 * 4096 * 2);  // [L][1024][4096]
    __bf16* LMT   = (__bf16*)carve((size_t)VV * 1024 * 2);         // [32000][1024]
    __bf16* x     = (__bf16*)carve((size_t)BT * EE * 2);           // bf16 residual
    __bf16* h     = (__bf16*)carve((size_t)BT * EE * 2);
    __bf16* qkv   = (__bf16*)carve((size_t)BT * 3072 * 2);
    __bf16* vT    = (__bf16*)carve((size_t)BB * HH * HSZ * TT * 2);  // [b][h][e][t]
    __bf16* mid   = (__bf16*)carve((size_t)BT * HID * 2);
    float*  lossv = (float*)carve((size_t)BT * 4);
    float*  part  = (float*)mid;   // [BT][250] sumexp partials; mid dead by then

    const dim3 blk(256);

    // weight transposes (f32 [K][N] -> bf16 [N][K]); QKV merged into one launch
    transpose_qkv<<<dim3(1, 16, 192), blk, 0, stream>>>(wq, wk, wv, WQKVT);
    transpose_conv<<<dim3(16, 16, 4), blk, 0, stream>>>(wo, WOT,   1024, 1024, 1048576, 4, 0, 1048576);
    transpose_conv<<<dim3(64, 16, 4), blk, 0, stream>>>(w1, W1T,   1024, 4096, 4194304, 4, 0, 4194304);
    transpose_conv<<<dim3(16, 64, 4), blk, 0, stream>>>(w2, W2T,   4096, 1024, 4194304, 4, 0, 4194304);
    transpose_conv<<<dim3(500, 16, 1), blk, 0, stream>>>(lm_w, LMT, 1024, 32000, 0, 1, 0, 0);

    embed_kernel<<<BT, blk, 0, stream>>>(idx, temb, x);

    for (int l = 0; l < LL; ++l) {
        ln_kernel<<<BT, blk, 0, stream>>>(x, ln1g + l * EE, ln1b + l * EE, h);
        gemm_bt<5, 0, 128><<<dim3(24, 32), blk, 0, stream>>>(h, WQKVT + (size_t)l * 3145728,
            nullptr, nullptr, qkv, vT, nullptr, BT, 3072, 1024);
        attn_kernel<<<dim3(64, 64), dim3(64), 0, stream>>>(qkv, vT, h);
        gemm_bt<2, 0, 64><<<dim3(16, 32), blk, 0, stream>>>(h, WOT + (size_t)l * 1048576,
            bo + l * EE, nullptr, x, nullptr, nullptr, BT, 1024, 1024);
        ln_kernel<<<BT, blk, 0, stream>>>(x, ln2g + l * EE, ln2b + l * EE, h);
        gemm_bt<1, 0, 128><<<dim3(32, 32), blk, 0, stream>>>(h, W1T + (size_t)l * 4194304,
            b1 + l * HID, nullptr, mid, nullptr, nullptr, BT, 4096, 1024);
        gemm_bt<2, 0, 64><<<dim3(16, 32), blk, 0, stream>>>(mid, W2T + (size_t)l * 4194304,
            b2 + l * EE, nullptr, x, nullptr, nullptr, BT, 1024, 4096);
    }
    ln_kernel<<<BT, blk, 0, stream>>>(x, lnfg, lnfb, h);
    // LM head: proven 128^2 kernel, XCD m-stripe map, fixed-max sumexp partials.
    gemm_bt<4, 1, 128><<<dim3(8000), blk, 0, stream>>>(h, LMT, lm_b, logits,
        nullptr, nullptr, part, BT, VV, 1024);
    loss_reduce<<<BT, blk, 0, stream>>>(part, logits, tgt, lossv, VV >> 7);
    loss_final<<<1, blk, 0, stream>>>(lossv, lossout);
}

// Round 15
// 1559.600 us; speedup vs baseline: 1.0270x; 1.0270x over previous
//
#include <hip/hip_runtime.h>
#include <hip/hip_bf16.h>
#include <math.h>

// ---------- constants ----------
#define BB 4
#define TT 1024
#define BT 4096          // B*T
#define EE 1024
#define HH 16
#define HSZ 64
#define LL 4
#define HID 4096
#define VV 32000
#define LOG2E 1.44269504f

typedef __attribute__((ext_vector_type(8))) __bf16 bf16x8;
typedef __attribute__((ext_vector_type(4))) __bf16 bf16x4;
typedef __attribute__((ext_vector_type(4))) float f32x4;

#define MFMA16(a, b, c) __builtin_amdgcn_mfma_f32_16x16x32_bf16((a), (b), (c), 0, 0, 0)

// swizzled offset in a 32-element (bf16) LDS row: 4 chunks of 8 elems,
// chunk ^= (row>>1)&3 -> 16B ds_read_b128 stays ~2-way conflict (free).
__device__ __forceinline__ int swz32(int row, int chunk) {
    return row * 32 + ((chunk ^ ((row >> 1) & 3)) << 3);
}

// async global->LDS, 16B per lane; LDS dest is WAVE-UNIFORM base + lane*16.
__device__ __forceinline__ void gload16(const __bf16* g, __bf16* l) {
    __builtin_amdgcn_global_load_lds(
        (const __attribute__((address_space(1))) unsigned int*)g,
        (__attribute__((address_space(3))) unsigned int*)l, 16, 0, 0);
}

// ---------- transpose + f32->bf16 convert:  in [R][C] f32  ->  out [C][R] bf16 ----------
__global__ __launch_bounds__(256) void transpose_conv(
    const float* __restrict__ in, __bf16* __restrict__ out,
    int R, int C, long ibs, int bdiv, long os1, long os2)
{
    __shared__ __bf16 tile[64][65];
    const int t = threadIdx.x;
    const int c0 = blockIdx.x * 64, r0 = blockIdx.y * 64;
    const int batch = blockIdx.z;
    const float* ib = in + (size_t)batch * ibs;
    __bf16* ob = out + (size_t)(batch / bdiv) * os1 + (size_t)(batch % bdiv) * os2;
#pragma unroll
    for (int p = 0; p < 4; ++p) {
        const int r = (t >> 4) + p * 16;
        const int c = (t & 15) * 4;
        float4 v = *(const float4*)(ib + (size_t)(r0 + r) * C + c0 + c);
        tile[c + 0][r] = (__bf16)v.x;
        tile[c + 1][r] = (__bf16)v.y;
        tile[c + 2][r] = (__bf16)v.z;
        tile[c + 3][r] = (__bf16)v.w;
    }
    __syncthreads();
#pragma unroll
    for (int p = 0; p < 2; ++p) {
        const int g = t + p * 256;
        const int co = g >> 3, ch = g & 7;
        bf16x8 vv;
#pragma unroll
        for (int j = 0; j < 8; ++j) vv[j] = tile[co][ch * 8 + j];
        *(bf16x8*)(ob + (size_t)(c0 + co) * R + r0 + ch * 8) = vv;
    }
}

// merged QKV-weight transpose: z in [0,192) -> which = z/64 (q/k/v), sub = z%64.
__global__ __launch_bounds__(256) void transpose_qkv(
    const float* __restrict__ wq, const float* __restrict__ wk,
    const float* __restrict__ wv, __bf16* __restrict__ out)
{
    __shared__ __bf16 tile[64][65];
    const int t = threadIdx.x;
    const int r0 = blockIdx.y * 64;
    const int which = blockIdx.z >> 6, sub = blockIdx.z & 63;
    const float* src = (which == 0) ? wq : (which == 1) ? wk : wv;
    const float* ib = src + (size_t)sub * 65536;
    __bf16* ob = out + (size_t)(sub >> 4) * 3145728 + (size_t)which * 1048576
               + (size_t)(sub & 15) * 65536;
#pragma unroll
    for (int p = 0; p < 4; ++p) {
        const int r = (t >> 4) + p * 16;
        const int c = (t & 15) * 4;
        float4 v = *(const float4*)(ib + (size_t)(r0 + r) * 64 + c);
        tile[c + 0][r] = (__bf16)v.x;
        tile[c + 1][r] = (__bf16)v.y;
        tile[c + 2][r] = (__bf16)v.z;
        tile[c + 3][r] = (__bf16)v.w;
    }
    __syncthreads();
#pragma unroll
    for (int p = 0; p < 2; ++p) {
        const int g = t + p * 256;
        const int co = g >> 3, ch = g & 7;
        bf16x8 vv;
#pragma unroll
        for (int j = 0; j < 8; ++j) vv[j] = tile[co][ch * 8 + j];
        *(bf16x8*)(ob + (size_t)co * 1024 + r0 + ch * 8) = vv;
    }
}

// ---------- embedding + sinusoidal positional encoding (bf16 residual) ----------
__global__ __launch_bounds__(256) void embed_kernel(
    const int* __restrict__ idx, const float* __restrict__ emb, __bf16* __restrict__ x)
{
    const int row = blockIdx.x, tid = threadIdx.x;
    const float pos = (float)(row & (TT - 1));
    const int tok = idx[row];
    const int cb = tid * 4;
    float4 ev = *(const float4*)(emb + (size_t)tok * EE + cb);
    const float kk = -9.2103403720f / (float)EE;   // -ln(10000)/E
    float pe[4];
#pragma unroll
    for (int j = 0; j < 4; ++j) {
        const int c = cb + j;
        const float div = expf(kk * (float)(c & ~1));
        const float ang = pos * div;
        pe[j] = (c & 1) ? cosf(ang) : sinf(ang);
    }
    bf16x4 r;
    r[0] = (__bf16)(ev.x * 32.0f + pe[0]);
    r[1] = (__bf16)(ev.y * 32.0f + pe[1]);
    r[2] = (__bf16)(ev.z * 32.0f + pe[2]);
    r[3] = (__bf16)(ev.w * 32.0f + pe[3]);
    *(bf16x4*)(x + (size_t)row * EE + cb) = r;
}

// ---------- LayerNorm (bf16 in -> bf16 out), ONE WAVE per row of 1024 ----------
// 4 rows per 256-thread block; no __syncthreads, wave-local reduction only.
__global__ __launch_bounds__(256) void ln_kernel(
    const __bf16* __restrict__ x, const float* __restrict__ g,
    const float* __restrict__ be, __bf16* __restrict__ out)
{
    const int tid = threadIdx.x, lane = tid & 63, w = tid >> 6;
    const int row = blockIdx.x * 4 + w;
    const __bf16* xr = x + (size_t)row * EE;
    float v[16];
    float s = 0.0f, ss = 0.0f;
#pragma unroll
    for (int p = 0; p < 4; ++p) {
        bf16x4 xv = *(const bf16x4*)(xr + p * 256 + lane * 4);
#pragma unroll
        for (int j = 0; j < 4; ++j) {
            const float f = (float)xv[j];
            v[p * 4 + j] = f;
            s += f;
            ss += f * f;
        }
    }
#pragma unroll
    for (int m = 1; m < 64; m <<= 1) { s += __shfl_xor(s, m); ss += __shfl_xor(ss, m); }
    const float mean = s * (1.0f / EE);
    const float var  = ss * (1.0f / EE) - mean * mean;
    const float rs   = rsqrtf(var + 1e-5f);
    __bf16* o = out + (size_t)row * EE;
#pragma unroll
    for (int p = 0; p < 4; ++p) {
        const int cb = p * 256 + lane * 4;
        float4 gv = *(const float4*)(g + cb);
        float4 bv = *(const float4*)(be + cb);
        bf16x4 ov;
        ov[0] = (__bf16)((v[p * 4 + 0] - mean) * rs * gv.x + bv.x);
        ov[1] = (__bf16)((v[p * 4 + 1] - mean) * rs * gv.y + bv.y);
        ov[2] = (__bf16)((v[p * 4 + 2] - mean) * rs * gv.z + bv.z);
        ov[3] = (__bf16)((v[p * 4 + 3] - mean) * rs * gv.w + bv.w);
        *(bf16x4*)(o + cb) = ov;
    }
}

// ---------- GEMM: C[M,N] = A[M,K](bf16) * Bt[N,K](bf16)^T  (+epilogue) ----------
// MODE 0: out bf16            MODE 1: out bf16, +bias, relu
// MODE 2: Cb(bf16) += acc + bias (residual stream)
// MODE 4: Cf32 = acc + bias, plus per-row fixed-max sumexp partial -> part[row][bn]
// GSWZ: 1D grid, XCD-stripe mapping (requires M==4096 -> 32 m-blocks).
template <int MODE, int GSWZ, int BN>
__global__ __launch_bounds__(256, 2) void gemm_bt(
    const __bf16* __restrict__ A, const __bf16* __restrict__ Bt,
    const float* __restrict__ bias, float* __restrict__ C,
    __bf16* __restrict__ Cb, float* __restrict__ part,
    int M, int N, int K)
{
    constexpr int JW  = BN / 32;   // j-fragments per wave
    constexpr int BSW = BN / 64;   // B staging gloads per wave
    __shared__ __bf16 As[128 * 32];
    __shared__ __bf16 Bs[BN * 32];
    __shared__ float redS[(MODE == 4) ? 128 : 1][2];

    const int tid = threadIdx.x;
    const int lane = tid & 63, wid = tid >> 6;
    const int wr = wid >> 1, wc = wid & 1;
    int bm, bn;
    if (GSWZ) {
        const int b = blockIdx.x;      // 8 XCDs x (4 m-stripes x N-sweep)
        const int j = b >> 3;
        bm = (b & 7) * 4 + (j & 3);
        bn = j >> 2;
    } else {
        bm = blockIdx.y; bn = blockIdx.x;
    }
    const int m0 = bm * 128, n0 = bn * BN;

    // staging: linear LDS dest, inverse-swizzled global source.
    size_t sA[2];  int loA[2];
#pragma unroll
    for (int c = 0; c < 2; ++c) {
        const int seg = wid * 2 + c;
        const int rl = seg * 16 + (lane >> 2);
        const int cl = (lane & 3) ^ ((rl >> 1) & 3);
        loA[c] = seg * 512;
        sA[c] = (size_t)(m0 + rl) * K + cl * 8;
    }
    size_t sB[BSW]; int loB[BSW];
#pragma unroll
    for (int c = 0; c < BSW; ++c) {
        const int seg = wid * BSW + c;
        const int rl = seg * 16 + (lane >> 2);
        const int cl = (lane & 3) ^ ((rl >> 1) & 3);
        loB[c] = seg * 512;
        sB[c] = (size_t)(n0 + rl) * K + cl * 8;
    }

    const int l15 = lane & 15, kch = lane >> 4;
    const int abase = swz32(wr * 64 + l15, kch);
    const int bbase = swz32(wc * (BN / 2) + l15, kch);

    f32x4 acc[4][JW] = {};

    const int nk = K >> 5;
    for (int kt = 0; kt < nk; ++kt) {
        const size_t ko = (size_t)kt * 32;
#pragma unroll
        for (int c = 0; c < 2; ++c)   gload16(A + sA[c] + ko, As + loA[c]);
#pragma unroll
        for (int c = 0; c < BSW; ++c) gload16(Bt + sB[c] + ko, Bs + loB[c]);
        __syncthreads();
        bf16x8 af[4], bfr[JW];
#pragma unroll
        for (int i = 0; i < 4; ++i)  af[i]  = *(const bf16x8*)(As + abase + i * 512);
#pragma unroll
        for (int j = 0; j < JW; ++j) bfr[j] = *(const bf16x8*)(Bs + bbase + j * 512);
#pragma unroll
        for (int i = 0; i < 4; ++i)
#pragma unroll
            for (int j = 0; j < JW; ++j)
                acc[i][j] = MFMA16(af[i], bfr[j], acc[i][j]);
        __syncthreads();
    }

    const int crow = m0 + wr * 64 + ((lane >> 4) << 2);
    const int ccol = n0 + wc * (BN / 2) + l15;
#pragma unroll
    for (int i = 0; i < 4; ++i)
#pragma unroll
        for (int j = 0; j < JW; ++j) {
            const int cc = ccol + j * 16;
#pragma unroll
            for (int r = 0; r < 4; ++r) {
                const size_t oidx = (size_t)(crow + i * 16 + r) * N + cc;
                float v = acc[i][j][r];
                if (MODE == 0) {
                    Cb[oidx] = (__bf16)v;
                } else if (MODE == 1) {
                    v += bias[cc];
                    Cb[oidx] = (__bf16)(v > 0.0f ? v : 0.0f);
                } else if (MODE == 2) {
                    Cb[oidx] = (__bf16)((float)Cb[oidx] + v + bias[cc]);
                } else {
                    C[oidx] = v + bias[cc];
                }
            }
        }

    if constexpr (MODE == 4) {
        // per-row sumexp (fixed max = 0) over this block's 128 columns
        const int lg = lane >> 4;
#pragma unroll
        for (int i = 0; i < 4; ++i)
#pragma unroll
            for (int r = 0; r < 4; ++r) {
                float sm = 0.0f;
#pragma unroll
                for (int j = 0; j < 4; ++j)
                    sm += exp2f((acc[i][j][r] + bias[ccol + j * 16]) * LOG2E);
                sm += __shfl_xor(sm, 1);
                sm += __shfl_xor(sm, 2);
                sm += __shfl_xor(sm, 4);
                sm += __shfl_xor(sm, 8);
                if (l15 == 0)
                    redS[wr * 64 + i * 16 + lg * 4 + r][wc] = sm;
            }
        __syncthreads();
        if (tid < 128)
            part[(size_t)(m0 + tid) * (N >> 7) + bn] = redS[tid][0] + redS[tid][1];
    }
}

// ---------- causal flash attention over packed qkv [BT][3072] ----------
// grid (B*H, T/16), ONE wave per block, 16 q-rows/wave, 32-key tiles.
// R13 structure (shuffle-free softmax, MFMA row-sum, LPT) + K-register
// prefetch: tile st's K fragments are loaded during tile st-1 so QK MFMAs
// start with operands ready.
__global__ __launch_bounds__(64, 4) void attn_kernel(
    const __bf16* __restrict__ qkv, __bf16* __restrict__ out)
{
    __shared__ __bf16 Pl[16 * 32];
    __shared__ __bf16 Vt[64 * 32];
    const int lane = threadIdx.x;
    const int bh = blockIdx.x, b = bh >> 4, hh = bh & 15;
    const int qbase = (63 - blockIdx.y) * 16;   // LPT: longest blocks first
    const int RS = 3 * EE;  // row stride of qkv
    const __bf16* qp = qkv + (size_t)(b * TT) * RS + hh * HSZ;
    const __bf16* kp = qp + EE;
    const __bf16* vp = qp + 2 * EE;
    const int l15 = lane & 15, lg = lane >> 4;

    bf16x8 aq[2];
#pragma unroll
    for (int e = 0; e < 2; ++e)
        aq[e] = *(const bf16x8*)(qp + (size_t)(qbase + l15) * RS + e * 32 + lg * 8);

    bf16x8 ones;
#pragma unroll
    for (int j = 0; j < 8; ++j) ones[j] = (__bf16)1.0f;

    f32x4 ao[4] = {};
    f32x4 lsum = {};           // exact row-sums of P, via MFMA(P, ones)
    float mrun[4];
#pragma unroll
    for (int r = 0; r < 4; ++r) mrun[r] = -1e30f;

    const int ntile = qbase / 32 + 1;

    // K fragment address: ne = n*2 + e
    auto kaddr = [&](int sbase, int ne) {
        return kp + (size_t)(sbase + (ne >> 1) * 16 + l15) * RS + (ne & 1) * 32 + lg * 8;
    };
    bf16x8 kf[4];
#pragma unroll
    for (int ne = 0; ne < 4; ++ne) kf[ne] = *(const bf16x8*)kaddr(0, ne);

    for (int st = 0; st < ntile; ++st) {
        const int sbase = st * 32;
        // QK^T with prefetched K (operands ready at iteration start)
        f32x4 as[2] = {};
        __builtin_amdgcn_s_setprio(1);
#pragma unroll
        for (int ne = 0; ne < 4; ++ne)
            as[ne >> 1] = MFMA16(aq[ne & 1], kf[ne], as[ne >> 1]);
        __builtin_amdgcn_s_setprio(0);
        // stage V tile into LDS (unchanged layout)
        {
            const int sl = lane >> 1;
            const int e0 = (lane & 1) * 32;
            const __bf16* vr = vp + (size_t)(sbase + sl) * RS + e0;
#pragma unroll
            for (int c = 0; c < 4; ++c) {
                bf16x8 vvv = *(const bf16x8*)(vr + c * 8);
#pragma unroll
                for (int j = 0; j < 8; ++j)
                    Vt[swz32(e0 + c * 8 + j, sl >> 3) + (sl & 7)] = vvv[j];
            }
        }
        // prefetch next tile's K fragments (clamped; tail reload unused)
        const int snext = (st + 1 < ntile) ? sbase + 32 : sbase;
#pragma unroll
        for (int ne = 0; ne < 4; ++ne) kf[ne] = *(const bf16x8*)kaddr(snext, ne);
        // scale + mask into registers; per-lane defer-max trigger check
        bool trig = false;
#pragma unroll
        for (int r = 0; r < 4; ++r) {
            const int qi = qbase + lg * 4 + r;
            float s0 = as[0][r] * 0.125f;
            float s1 = as[1][r] * 0.125f;
            if (sbase + l15 > qi)      s0 = -1e30f;
            if (sbase + 16 + l15 > qi) s1 = -1e30f;
            as[0][r] = s0; as[1][r] = s1;
            trig = trig || (s0 > mrun[r] + 8.0f) || (s1 > mrun[r] + 8.0f);
        }
        if (__any(trig)) {   // rare (typically tile 0 only): full rescale
#pragma unroll
            for (int r = 0; r < 4; ++r) {
                float rm = fmaxf(as[0][r], as[1][r]);
                rm = fmaxf(rm, __shfl_xor(rm, 1));
                rm = fmaxf(rm, __shfl_xor(rm, 2));
                rm = fmaxf(rm, __shfl_xor(rm, 4));
                rm = fmaxf(rm, __shfl_xor(rm, 8));
                const float mnew = fmaxf(mrun[r], rm);
                const float alpha = exp2f((mrun[r] - mnew) * LOG2E);
                lsum[r] *= alpha;
#pragma unroll
                for (int n = 0; n < 4; ++n) ao[n][r] *= alpha;
                mrun[r] = mnew;
            }
        }
#pragma unroll
        for (int r = 0; r < 4; ++r) {
            const float p0 = exp2f((as[0][r] - mrun[r]) * LOG2E);  // <= e^8
            const float p1 = exp2f((as[1][r] - mrun[r]) * LOG2E);
            const int prow = lg * 4 + r;
            Pl[swz32(prow, l15 >> 3) + (l15 & 7)] = (__bf16)p0;
            Pl[swz32(prow, (16 + l15) >> 3) + (l15 & 7)] = (__bf16)p1;
        }
        asm volatile("s_waitcnt lgkmcnt(0)" ::: "memory");
        bf16x8 pa = *(const bf16x8*)(&Pl[swz32(l15, lg)]);
        __builtin_amdgcn_s_setprio(1);
#pragma unroll
        for (int n = 0; n < 4; ++n) {
            bf16x8 bv = *(const bf16x8*)(&Vt[swz32(n * 16 + l15, lg)]);
            ao[n] = MFMA16(pa, bv, ao[n]);
        }
        lsum = MFMA16(pa, ones, lsum);   // exact row-sum accumulation
        __builtin_amdgcn_s_setprio(0);
        asm volatile("s_waitcnt lgkmcnt(0)" ::: "memory");
    }
#pragma unroll
    for (int r = 0; r < 4; ++r) {
        const float inv = 1.0f / lsum[r];
        const int row = qbase + lg * 4 + r;
#pragma unroll
        for (int n = 0; n < 4; ++n)
            out[(size_t)(b * TT + row) * EE + hh * HSZ + n * 16 + l15] =
                (__bf16)(ao[n][r] * inv);
    }
}

// ---------- merge per-block sumexp partials + target gather ----------
__global__ __launch_bounds__(256) void loss_reduce(
    const float* __restrict__ part, const float* __restrict__ logits,
    const int* __restrict__ tgt, float* __restrict__ lossv, int NP)
{
    __shared__ float rs2[4];
    const int row = blockIdx.x, tid = threadIdx.x;
    float s = (tid < NP) ? part[(size_t)row * NP + tid] : 0.0f;
#pragma unroll
    for (int k = 1; k < 64; k <<= 1) s += __shfl_xor(s, k);
    if ((tid & 63) == 0) rs2[tid >> 6] = s;
    __syncthreads();
    if (tid == 0) {
        const float S = rs2[0] + rs2[1] + rs2[2] + rs2[3];
        lossv[row] = logf(S) - logits[(size_t)row * VV + tgt[row]];
    }
}

__global__ __launch_bounds__(256) void loss_final(const float* __restrict__ lossv, float* __restrict__ out)
{
    __shared__ float red[4];
    const int tid = threadIdx.x;
    float s = 0.0f;
    for (int i = tid; i < BT; i += 256) s += lossv[i];
#pragma unroll
    for (int k = 1; k < 64; k <<= 1) s += __shfl_xor(s, k);
    if ((tid & 63) == 0) red[tid >> 6] = s;
    __syncthreads();
    if (tid == 0) out[0] = (red[0] + red[1] + red[2] + red[3]) * (1.0f / BT);
}

// ---------- launcher ----------
extern "C" void kernel_launch(void* const* d_in, const int* in_sizes, int n_in,
                              void* d_out, int out_size, void* d_ws, size_t ws_size,
                              hipStream_t stream)
{
    const int*   idx   = (const int*)d_in[0];
    const int*   tgt   = (const int*)d_in[1];
    const float* temb  = (const float*)d_in[2];
    const float* ln1g  = (const float*)d_in[3];
    const float* ln1b  = (const float*)d_in[4];
    const float* wq    = (const float*)d_in[5];
    const float* wk    = (const float*)d_in[6];
    const float* wv    = (const float*)d_in[7];
    const float* wo    = (const float*)d_in[8];
    const float* bo    = (const float*)d_in[9];
    const float* ln2g  = (const float*)d_in[10];
    const float* ln2b  = (const float*)d_in[11];
    const float* w1    = (const float*)d_in[12];
    const float* b1    = (const float*)d_in[13];
    const float* w2    = (const float*)d_in[14];
    const float* b2    = (const float*)d_in[15];
    const float* lnfg  = (const float*)d_in[16];
    const float* lnfb  = (const float*)d_in[17];
    const float* lm_w  = (const float*)d_in[18];
    const float* lm_b  = (const float*)d_in[19];

    float* logits  = (float*)d_out;
    float* lossout = logits + (size_t)BT * VV;

    char* ws = (char*)d_ws;
    size_t off = 0;
    auto carve = [&](size_t bytes) {
        void* p = ws + off;
        off += (bytes + 255) & ~(size_t)255;
        return p;
    };
    __bf16* WQKVT = (__bf16*)carve((size_t)LL * 3072 * 1024 * 2);  // [L][3072][1024]
    __bf16* WOT   = (__bf16*)carve((size_t)LL * 1024 * 1024 * 2);  // [L][1024][1024]
    __bf16* W1T   = (__bf16*)carve((size_t)LL * 4096 * 1024 * 2);  // [L][4096][1024]
    __bf16* W2T   = (__bf16*)carve((size_t)LL * 1024 * 4096 * 2);  // [L][1024][4096]
    __bf16* LMT   = (__bf16*)carve((size_t)VV * 1024 * 2);         // [32000][1024]
    __bf16* x     = (__bf16*)carve((size_t)BT * EE * 2);           // bf16 residual
    __bf16* h     = (__bf16*)carve((size_t)BT * EE * 2);
    __bf16* qkv   = (__bf16*)carve((size_t)BT * 3072 * 2);
    __bf16* mid   = (__bf16*)carve((size_t)BT * HID * 2);
    float*  lossv = (float*)carve((size_t)BT * 4);
    float*  part  = (float*)mid;   // [BT][250] sumexp partials; mid dead by then

    const dim3 blk(256);

    // weight transposes (f32 [K][N] -> bf16 [N][K]); QKV merged into one launch
    transpose_qkv<<<dim3(1, 16, 192), blk, 0, stream>>>(wq, wk, wv, WQKVT);
    transpose_conv<<<dim3(16, 16, 4), blk, 0, stream>>>(wo, WOT,   1024, 1024, 1048576, 4, 0, 1048576);
    transpose_conv<<<dim3(64, 16, 4), blk, 0, stream>>>(w1, W1T,   1024, 4096, 4194304, 4, 0, 4194304);
    transpose_conv<<<dim3(16, 64, 4), blk, 0, stream>>>(w2, W2T,   4096, 1024, 4194304, 4, 0, 4194304);
    transpose_conv<<<dim3(500, 16, 1), blk, 0, stream>>>(lm_w, LMT, 1024, 32000, 0, 1, 0, 0);

    embed_kernel<<<BT, blk, 0, stream>>>(idx, temb, x);

    for (int l = 0; l < LL; ++l) {
        ln_kernel<<<BT / 4, blk, 0, stream>>>(x, ln1g + l * EE, ln1b + l * EE, h);
        gemm_bt<0, 0, 128><<<dim3(24, 32), blk, 0, stream>>>(h, WQKVT + (size_t)l * 3145728,
            nullptr, nullptr, qkv, nullptr, BT, 3072, 1024);
        attn_kernel<<<dim3(64, 64), dim3(64), 0, stream>>>(qkv, h);
        gemm_bt<2, 0, 64><<<dim3(16, 32), blk, 0, stream>>>(h, WOT + (size_t)l * 1048576,
            bo + l * EE, nullptr, x, nullptr, BT, 1024, 1024);
        ln_kernel<<<BT / 4, blk, 0, stream>>>(x, ln2g + l * EE, ln2b + l * EE, h);
        gemm_bt<1, 0, 128><<<dim3(32, 32), blk, 0, stream>>>(h, W1T + (size_t)l * 4194304,
            b1 + l * HID, nullptr, mid, nullptr, BT, 4096, 1024);
        gemm_bt<2, 0, 64><<<dim3(16, 32), blk, 0, stream>>>(mid, W2T + (size_t)l * 4194304,
            b2 + l * EE, nullptr, x, nullptr, BT, 1024, 4096);
    }
    ln_kernel<<<BT / 4, blk, 0, stream>>>(x, lnfg, lnfb, h);
    // LM head: proven 128^2 kernel, XCD m-stripe map, fixed-max sumexp partials.
    gemm_bt<4, 1, 128><<<dim3(8000), blk, 0, stream>>>(h, LMT, lm_b, logits,
        nullptr, part, BT, VV, 1024);
    loss_reduce<<<BT, blk, 0, stream>>>(part, logits, tgt, lossv, VV >> 7);
    loss_final<<<1, blk, 0, stream>>>(lossv, lossout);
}